// Round 1
// baseline (466.802 us; speedup 1.0000x reference)
//
#include <hip/hip_runtime.h>

// ---------------------------------------------------------------------------
// StackedLSTMCell: L=2, B=16384, S=512.
//   per layer: z = x@W + h_tm1@U + b ; (i,f,g,o) = split(z)
//              c = sig(f)*c_tm1 + sig(i)*tanh(g) ; h = sig(o)*tanh(c)
//   h_tm1 = prev_c[l], c_tm1 = prev_h[l] (NNI naming swap). x_{l+1} = c_l.
// Strategy: bf16 MFMA GEMM (threshold 7.75e-2 allows bf16 quantization).
//   Wcat[l] = [W;U]^T repacked to [N=2048][K=1024] bf16 with gate-interleaved
//   N so a wave's 4 n-tiles == the 4 gates of the same 16 hidden units ->
//   LSTM elementwise fuses into GEMM epilogue lane-locally.
// ---------------------------------------------------------------------------

#define B_DIM   16384
#define S_DIM   512
#define K_DIM   1024          // concat K = S (input) + S (recurrent)
#define N_DIM   2048          // 4 gates * S
#define BS      (B_DIM * S_DIM)

typedef __bf16 bf16x8 __attribute__((ext_vector_type(8)));
typedef float  f32x4  __attribute__((ext_vector_type(4)));

__device__ __forceinline__ void async16(const void* g, void* l) {
    __builtin_amdgcn_global_load_lds(
        (const __attribute__((address_space(1))) void*)g,
        (__attribute__((address_space(3))) void*)l,
        16, 0, 0);
}

__device__ __forceinline__ float sigm(float x) { return 1.f / (1.f + __expf(-x)); }
__device__ __forceinline__ float tanh_f(float x) { return 1.f - 2.f / (__expf(2.f * x) + 1.f); }

// ---------------------------------------------------------------------------
// Repack weights: Wcat[l][new_n][k] (bf16), k<512 from kernels, k>=512 from
// rec_kernels. new_n = (s/16)*64 + gate*16 + (s%16), orig col = gate*512 + s.
// LDS tile transpose for coalescing. Grid: 1024 blocks x 256.
// ---------------------------------------------------------------------------
__global__ __launch_bounds__(256) void repack_w(const float* __restrict__ kern,
                                                const float* __restrict__ rker,
                                                __bf16* __restrict__ Wcat) {
    int bid   = blockIdx.x;
    int ntile = bid & 31;        // 32 tiles of 64 orig cols
    int kt    = (bid >> 5) & 7;  // 8 tiles of 64 k
    int srcm  = (bid >> 8) & 1;  // 0 = kern, 1 = rec
    int l     = bid >> 9;

    __shared__ float tile[64][65];
    const float* src = (srcm ? rker : kern) + l * (S_DIM * N_DIM);
    int k0 = kt * 64, n0 = ntile * 64;
    int t = threadIdx.x;

    for (int i = 0; i < 4; ++i) {
        int lin4 = i * 256 + t;          // 1024 float4 slots
        int row  = lin4 >> 4;
        int c4   = (lin4 & 15) << 2;
        float4 v = *(const float4*)(src + (k0 + row) * N_DIM + n0 + c4);
        tile[row][c4]     = v.x;
        tile[row][c4 + 1] = v.y;
        tile[row][c4 + 2] = v.z;
        tile[row][c4 + 3] = v.w;
    }
    __syncthreads();

    int gate = n0 >> 9;                  // whole tile one gate (64 | 512)
    for (int it = 0; it < 2; ++it) {
        int slot = it * 256 + t;         // 512 slots: 64 cols x 8 k-segs
        int c    = slot >> 3;
        int seg  = slot & 7;
        int n    = n0 + c;
        int s    = n & 511;
        int new_n = ((s >> 4) << 6) + (gate << 4) + (s & 15);
        int kc = srcm * 512 + k0 + seg * 8;
        bf16x8 o;
        #pragma unroll
        for (int j = 0; j < 8; ++j) o[j] = (__bf16)tile[seg * 8 + j][c];
        *(bf16x8*)(Wcat + (size_t)(l * N_DIM + new_n) * K_DIM + kc) = o;
    }
}

// ---------------------------------------------------------------------------
// Convert activations to bf16 concat layout.
//   sec0: x         -> A0[:, 0:512]
//   sec1: prev_c[0] -> A0[:, 512:1024]
//   sec2: prev_c[1] -> A1[:, 512:1024]
// Grid: 12288 x 256 (3 * 1M threads, 8 elems each).
// ---------------------------------------------------------------------------
__global__ __launch_bounds__(256) void convert_A(const float* __restrict__ x,
                                                 const float* __restrict__ prev_c,
                                                 __bf16* __restrict__ A0,
                                                 __bf16* __restrict__ A1) {
    int id  = blockIdx.x * 256 + threadIdx.x;
    int sec = id >> 20;
    int e   = id & ((1 << 20) - 1);
    int r   = e >> 6;
    int c   = (e & 63) << 3;
    const float* src;
    __bf16* dst;
    if (sec == 0)      { src = x + (size_t)r * S_DIM + c;            dst = A0 + (size_t)r * K_DIM + c; }
    else if (sec == 1) { src = prev_c + (size_t)r * S_DIM + c;       dst = A0 + (size_t)r * K_DIM + 512 + c; }
    else               { src = prev_c + (size_t)BS + (size_t)r * S_DIM + c; dst = A1 + (size_t)r * K_DIM + 512 + c; }
    float4 v0 = *(const float4*)(src);
    float4 v1 = *(const float4*)(src + 4);
    bf16x8 o;
    o[0] = (__bf16)v0.x; o[1] = (__bf16)v0.y; o[2] = (__bf16)v0.z; o[3] = (__bf16)v0.w;
    o[4] = (__bf16)v1.x; o[5] = (__bf16)v1.y; o[6] = (__bf16)v1.z; o[7] = (__bf16)v1.w;
    *(bf16x8*)dst = o;
}

// ---------------------------------------------------------------------------
// Fused GEMM + LSTM cell. 128x128 tile, BK=32, 4 waves (2x2), each wave
// 64x64 via 4x4 grid of 16x16x32 bf16 MFMA. Wave's 4 n-tiles = gates 0..3 of
// the same 16 hidden units (per N permutation).
// ---------------------------------------------------------------------------
__global__ __launch_bounds__(256) void lstm_gemm(const __bf16* __restrict__ A,
                                                 const __bf16* __restrict__ W,
                                                 const float* __restrict__ c_tm1p,
                                                 const float* __restrict__ bias,
                                                 float* __restrict__ outh,
                                                 float* __restrict__ outc,
                                                 __bf16* __restrict__ A_next) {
    __shared__ __align__(16) __bf16 As[128 * 32];
    __shared__ __align__(16) __bf16 Bs[128 * 32];

    int tid  = threadIdx.x;
    int w    = tid >> 6;
    int lane = tid & 63;
    int wm   = w >> 1, wn = w & 1;
    int rowA0 = blockIdx.x * 128;   // batch rows
    int rowB0 = blockIdx.y * 128;   // new_n rows

    f32x4 acc[4][4];
    #pragma unroll
    for (int i = 0; i < 4; ++i)
        #pragma unroll
        for (int j = 0; j < 4; ++j) acc[i][j] = (f32x4){0.f, 0.f, 0.f, 0.f};

    // staging geometry: tile is [128 rows][32 k] bf16 = 8KB, row = 64B.
    // chunk ci = q*4 + w; flat byte = ci*1024 + lane*16.
    int flat0 = (0 * 4 + w) * 1024 + lane * 16;
    int flat1 = (1 * 4 + w) * 1024 + lane * 16;
    int r0 = flat0 >> 6, c0 = (flat0 & 63) >> 1;
    int r1 = flat1 >> 6, c1 = (flat1 & 63) >> 1;
    const __bf16* Ag0 = A + (size_t)(rowA0 + r0) * K_DIM + c0;
    const __bf16* Ag1 = A + (size_t)(rowA0 + r1) * K_DIM + c1;
    const __bf16* Bg0 = W + (size_t)(rowB0 + r0) * K_DIM + c0;
    const __bf16* Bg1 = W + (size_t)(rowB0 + r1) * K_DIM + c1;

    int l15  = lane & 15;
    int quad = lane >> 4;

    for (int k0 = 0; k0 < K_DIM; k0 += 32) {
        __syncthreads();   // prior iter done with LDS
        async16(Ag0 + k0, (char*)As + flat0);
        async16(Ag1 + k0, (char*)As + flat1);
        async16(Bg0 + k0, (char*)Bs + flat0);
        async16(Bg1 + k0, (char*)Bs + flat1);
        __syncthreads();   // drains vmcnt -> tiles resident

        bf16x8 af[4], bfr[4];
        #pragma unroll
        for (int mt = 0; mt < 4; ++mt)
            af[mt] = *(const bf16x8*)((const char*)As + (wm * 64 + mt * 16 + l15) * 64 + quad * 16);
        #pragma unroll
        for (int nt = 0; nt < 4; ++nt)
            bfr[nt] = *(const bf16x8*)((const char*)Bs + (wn * 64 + nt * 16 + l15) * 64 + quad * 16);
        #pragma unroll
        for (int mt = 0; mt < 4; ++mt)
            #pragma unroll
            for (int nt = 0; nt < 4; ++nt)
                acc[mt][nt] = __builtin_amdgcn_mfma_f32_16x16x32_bf16(af[mt], bfr[nt], acc[mt][nt], 0, 0, 0);
    }

    // Epilogue: lane's hidden unit u = block64*16 + (lane&15); gate = nt.
    int block64 = (rowB0 + wn * 64) >> 6;
    int u = block64 * 16 + l15;
    float bg[4];
    #pragma unroll
    for (int nt = 0; nt < 4; ++nt) bg[nt] = bias[nt * 512 + u];

    #pragma unroll
    for (int mt = 0; mt < 4; ++mt) {
        int Rbase = rowA0 + wm * 64 + mt * 16 + quad * 4;
        #pragma unroll
        for (int reg = 0; reg < 4; ++reg) {
            int R = Rbase + reg;
            float zi = acc[mt][0][reg] + bg[0];
            float zf = acc[mt][1][reg] + bg[1];
            float zg = acc[mt][2][reg] + bg[2];
            float zo = acc[mt][3][reg] + bg[3];
            float ct = c_tm1p[(size_t)R * S_DIM + u];
            float cv = sigm(zf) * ct + sigm(zi) * tanh_f(zg);
            float hv = sigm(zo) * tanh_f(cv);
            outh[(size_t)R * S_DIM + u] = hv;
            outc[(size_t)R * S_DIM + u] = cv;
            if (A_next) A_next[(size_t)R * K_DIM + u] = (__bf16)cv;
        }
    }
}

// ---------------------------------------------------------------------------
extern "C" void kernel_launch(void* const* d_in, const int* in_sizes, int n_in,
                              void* d_out, int out_size, void* d_ws, size_t ws_size,
                              hipStream_t stream) {
    const float* x      = (const float*)d_in[0];
    const float* prev_c = (const float*)d_in[1];
    const float* prev_h = (const float*)d_in[2];
    const float* kern   = (const float*)d_in[3];
    const float* rker   = (const float*)d_in[4];
    const float* bias   = (const float*)d_in[5];
    float* out = (float*)d_out;

    char* ws = (char*)d_ws;
    __bf16* Wcat = (__bf16*)ws;                              // 2*2048*1024 bf16 = 8 MB
    __bf16* A0   = (__bf16*)(ws + (size_t)8  * 1024 * 1024); // 16384*1024 bf16 = 32 MB
    __bf16* A1   = (__bf16*)(ws + (size_t)40 * 1024 * 1024); // 32 MB

    convert_A<<<12288, 256, 0, stream>>>(x, prev_c, A0, A1);
    repack_w<<<1024, 256, 0, stream>>>(kern, rker, Wcat);

    dim3 grid(B_DIM / 128, N_DIM / 128);
    // layer 0: h_tm1 = prev_c[0] (already in A0), c_tm1 = prev_h[0]
    lstm_gemm<<<grid, 256, 0, stream>>>(A0, Wcat,
                                        prev_h,            bias,
                                        out,               out + (size_t)BS,
                                        A1);
    // layer 1: x = c0 (A1 low half, written by layer-0 epilogue)
    lstm_gemm<<<grid, 256, 0, stream>>>(A1, Wcat + (size_t)N_DIM * K_DIM,
                                        prev_h + (size_t)BS, bias + N_DIM,
                                        out + (size_t)2 * BS, out + (size_t)3 * BS,
                                        nullptr);
}